// Round 1
// baseline (822.798 us; speedup 1.0000x reference)
//
#include <hip/hip_runtime.h>
#include <math.h>

#define N_NODES 100000
#define N_EDGES 1600000
#define D 64
#define RPB 128                  // rows per bucket
#define NBUK 782                 // ceil(N_NODES/128)
#define CAP 3072                 // LDS edge buffer (bucket mean 2048, +22 sigma)
#define NGB 782                  // gemm blocks (128 rows each)
#define NHB 196                  // sort blocks
#define EPB 8192                 // edges per sort block (196*8192 >= 1.6M)
#define POFF_STRIDE 200          // padded row stride of poff[b][hb]
#define ACCS 65                  // acc row stride (pad: bank = (row+8dg+k)%32)

typedef unsigned int u32;
typedef unsigned short u16;

static __device__ __forceinline__ u32 f2bf(float x) {   // RNE fp32->bf16 (low 16)
    u32 u = __float_as_uint(x);
    u32 r = u + 0x7FFFu + ((u >> 16) & 1u);
    return r >> 16;
}
static __device__ __forceinline__ u32 pack2(float a, float b) {
    return f2bf(a) | (f2bf(b) << 16);
}
static __device__ __forceinline__ float bflo(u32 u) { return __uint_as_float(u << 16); }
static __device__ __forceinline__ float bfhi(u32 u) { return __uint_as_float(u & 0xFFFF0000u); }
static __device__ __forceinline__ float selu(float x) {
    const float scale = 1.0507009873554805f;
    const float alpha = 1.6732632423543772f;
    return x > 0.f ? scale * x : scale * alpha * (expf(x) - 1.f);
}
// native ds_add_f32 (plain atomicAdd on LDS float may expand to a CAS loop
// depending on denormal-mode function attrs; unsafeAtomicAdd forces the HW op)
static __device__ __forceinline__ void fadd_lds(float* p, float v) {
    unsafeAtomicAdd(p, v);
}

// ---------------------------------------------------------------------------
// K1 fused (unchanged). Blocks [0,782): bf16 h = feat @ kern (register-tiled
// 4r x 8c, kern in LDS, feat streamed from global). Blocks [782,978): in-LDS
// counting sort of 8192 edges by bucket -> private contiguous sedge region +
// 783 bucket offsets. erow staged in LDS (read once); no global atomics.
// ---------------------------------------------------------------------------
__global__ __launch_bounds__(256) void fused_gemm_sort(
    const float* __restrict__ feat, const float* __restrict__ kern,
    const int* __restrict__ erow, const int* __restrict__ ecol,
    const float* __restrict__ eval, u16* __restrict__ hbf,
    int2* __restrict__ sedge, u32* __restrict__ poff)
{
    __shared__ u32 smem[10795];  // 43.2 KB: gemm uses 16 KB; sort uses all
    const int t = threadIdx.x;

    if (blockIdx.x < NGB) {
        float* ks = (float*)smem;   // 64x64 kernel, row-major [k][c]
        {
            const float4* k4 = (const float4*)kern;
            float4* ks4 = (float4*)ks;
            #pragma unroll
            for (int i = 0; i < 4; i++) ks4[t + 256 * i] = k4[t + 256 * i];
        }
        __syncthreads();

        const int cgi  = t & 7;                      // 8 col-groups (8 cols)
        const int rg   = t >> 3;                     // 32 row-groups (4 rows)
        const int row0 = blockIdx.x * RPB + rg * 4;

        float4 acc[4][2];
        #pragma unroll
        for (int r = 0; r < 4; r++)
            #pragma unroll
            for (int i = 0; i < 2; i++)
                acc[r][i] = make_float4(0.f, 0.f, 0.f, 0.f);

        #pragma unroll 4
        for (int s = 0; s < 16; s++) {               // k4-step: 4 k-values
            float4 f[4];
            #pragma unroll
            for (int r = 0; r < 4; r++) {
                int row = min(row0 + r, N_NODES - 1);
                f[r] = ((const float4*)(feat + (size_t)row * D))[s];
            }
            float4 kk[4][2];
            #pragma unroll
            for (int kv = 0; kv < 4; kv++)
                #pragma unroll
                for (int i = 0; i < 2; i++)
                    kk[kv][i] = ((const float4*)(ks + (s * 4 + kv) * D))[cgi * 2 + i];
            #pragma unroll
            for (int r = 0; r < 4; r++) {
                #pragma unroll
                for (int kv = 0; kv < 4; kv++) {
                    float fv = (&f[r].x)[kv];
                    #pragma unroll
                    for (int i = 0; i < 2; i++) {
                        acc[r][i].x += fv * kk[kv][i].x;
                        acc[r][i].y += fv * kk[kv][i].y;
                        acc[r][i].z += fv * kk[kv][i].z;
                        acc[r][i].w += fv * kk[kv][i].w;
                    }
                }
            }
        }

        #pragma unroll
        for (int r = 0; r < 4; r++) {
            int row = row0 + r;
            if (row < N_NODES) {
                uint4 o;
                o.x = pack2(acc[r][0].x, acc[r][0].y);
                o.y = pack2(acc[r][0].z, acc[r][0].w);
                o.z = pack2(acc[r][1].x, acc[r][1].y);
                o.w = pack2(acc[r][1].z, acc[r][1].w);
                ((uint4*)(hbf + (size_t)row * D))[cgi] = o;
            }
        }
    } else {
        u32* er   = smem;                 // 8192: staged erow
        u32* c    = smem + 8192;          // 782 counts
        u32* o    = c + NBUK;             // 783 offsets
        u32* cu   = o + NBUK + 1;         // 782 cursors
        u32* part = cu + NBUK;            // 256 scan partials

        for (int i = t; i < NBUK; i += 256) c[i] = 0u;
        __syncthreads();

        const int hb   = blockIdx.x - NGB;
        const int base = hb * EPB;

        // pass 1: stage erow in LDS + bucket count (native u32 LDS atomics)
        #pragma unroll
        for (int k = 0; k < 32; k++) {
            int i = base + k * 256 + t;
            u32 r = 0xFFFFFFFFu;
            if (i < N_EDGES) { r = (u32)erow[i]; atomicAdd(&c[r >> 7], 1u); }
            er[k * 256 + t] = r;
        }
        __syncthreads();

        // blocked exclusive scan over 782 counts (4 per thread + 256-wide HS)
        const int i0 = t * 4;
        {
            u32 p = 0u;
            #pragma unroll
            for (int j = 0; j < 4; j++) { int i = i0 + j; if (i < NBUK) p += c[i]; }
            part[t] = p;
        }
        __syncthreads();
        for (int d = 1; d < 256; d <<= 1) {
            u32 a = (t >= d) ? part[t - d] : 0u;
            __syncthreads();
            part[t] += a;
            __syncthreads();
        }
        {
            u32 run = (t > 0) ? part[t - 1] : 0u;
            #pragma unroll
            for (int j = 0; j < 4; j++) {
                int i = i0 + j;
                if (i < NBUK) { o[i] = run; cu[i] = run; run += c[i]; }
            }
            if (t == 255) o[NBUK] = part[255];   // total edges in this block
        }
        __syncthreads();

        // pass 2: scatter into private contiguous region (L2-resident 64 KB)
        #pragma unroll
        for (int k = 0; k < 32; k++) {
            int i = base + k * 256 + t;
            if (i < N_EDGES) {
                u32 r = er[k * 256 + t];
                u32 rk = atomicAdd(&cu[r >> 7], 1u);
                sedge[(size_t)hb * EPB + rk] =
                    make_int2(ecol[i] | (int)((r & 127u) << 17),
                              __float_as_int(eval[i]));
            }
        }

        // publish 783 offsets, transposed for coalesced agg reads
        for (int i = t; i <= NBUK; i += 256)
            poff[(size_t)i * POFF_STRIDE + hb] = o[i];
    }
}

// ---------------------------------------------------------------------------
// K2 v2: aggregation via LDS fp32 atomic scatter-accumulate.
//  - run descriptors loaded coalesced (196-wide) + in-LDS scan -> deterministic
//    append bases (no gcur atomic, no dependent poff load chains)
//  - NO row sort: edges processed edge-parallel (8 lanes/edge, 8 dims/lane),
//    each lane does 8 mul + 8 ds_add_f32 into acc[row][dim] (stride-65 pad:
//    bank = (row + 8*dg + k) % 32, rows random -> ~2-way aliasing = free)
//  - iterations fully independent -> deep load pipelining on the hbf gather
//  - epilogue: 1024 threads = 128 rows x 8 dim-groups, skip/bias + SELU
// ---------------------------------------------------------------------------
__global__ __launch_bounds__(1024) void agg_kernel(
    const u32* __restrict__ poff, const int2* __restrict__ sedge,
    const u16* __restrict__ hbf, const float* __restrict__ skip,
    const float* __restrict__ bias, float* __restrict__ out)
{
    __shared__ int2  eA[CAP];            // 24.0 KB staged edges
    __shared__ float acc[RPB * ACCS];    // 33.3 KB fp32 accumulators
    __shared__ u32   rs0[NHB];
    __shared__ u32   rlen[NHB];
    __shared__ u32   rbase[NHB];
    __shared__ u32   scn[256];

    const int t = threadIdx.x;
    const int w = t >> 6;
    const int lane = t & 63;
    const int b = blockIdx.x;

    // zero accumulators
    for (int i = t; i < RPB * ACCS; i += 1024) acc[i] = 0.f;

    // run descriptors: coalesced 196-wide loads (was: per-run dependent loads)
    if (t < NHB) {
        u32 s0 = poff[(size_t)b * POFF_STRIDE + t];
        u32 s1 = poff[(size_t)(b + 1) * POFF_STRIDE + t];
        rs0[t]  = s0;
        rlen[t] = s1 - s0;
    }
    __syncthreads();

    // Hillis-Steele inclusive scan over 256 (196 real) -> append bases
    if (t < 256) scn[t] = (t < NHB) ? rlen[t] : 0u;
    __syncthreads();
    for (int d = 1; d < 256; d <<= 1) {
        u32 a = 0u;
        if (t < 256 && t >= d) a = scn[t - d];
        __syncthreads();
        if (t < 256) scn[t] += a;
        __syncthreads();
    }
    if (t < NHB) rbase[t] = scn[t] - rlen[t];
    __syncthreads();

    const u32 cnt = min(scn[NHB - 1], (u32)CAP);

    // phase A: append 196 runs into eA (wave per run, deterministic bases)
    for (int hb = w; hb < NHB; hb += 16) {
        u32 base = rbase[hb], s0 = rs0[hb], len = rlen[hb];
        for (u32 j = (u32)lane; j < len; j += 64u)
            if (base + j < (u32)CAP)
                eA[base + j] = sedge[(size_t)hb * EPB + s0 + j];
    }
    __syncthreads();

    // phase C: edge-parallel gather + LDS atomic accumulate
    const int dg = t & 7;                 // 8 dims (one uint4) per lane
    #pragma unroll 4
    for (u32 j = (u32)(t >> 3); j < cnt; j += 128u) {
        int2 e = eA[j];                   // 8-lane broadcast read
        u32 rl = (u32)e.x >> 17;
        float v = __int_as_float(e.y);
        uint4 h = ((const uint4*)(hbf + (size_t)((u32)e.x & 0x1FFFFu) * D))[dg];
        float* ap = acc + rl * ACCS + dg * 8;
        fadd_lds(ap + 0, v * bflo(h.x));
        fadd_lds(ap + 1, v * bfhi(h.x));
        fadd_lds(ap + 2, v * bflo(h.y));
        fadd_lds(ap + 3, v * bfhi(h.y));
        fadd_lds(ap + 4, v * bflo(h.z));
        fadd_lds(ap + 5, v * bfhi(h.z));
        fadd_lds(ap + 6, v * bflo(h.w));
        fadd_lds(ap + 7, v * bfhi(h.w));
    }
    __syncthreads();

    // epilogue: 1024 threads = 128 rows x 8 dim-groups, fully parallel
    const int rows = min(RPB, N_NODES - b * RPB);
    const int row = t >> 3;
    if (row < rows) {
        const int grow = b * RPB + row;
        uint4 hr = ((const uint4*)(hbf + (size_t)grow * D))[dg];
        float4 s0 = ((const float4*)skip)[2 * dg];
        float4 s1 = ((const float4*)skip)[2 * dg + 1];
        float4 b0 = ((const float4*)bias)[2 * dg];
        float4 b1 = ((const float4*)bias)[2 * dg + 1];
        const float* ap = acc + row * ACCS + dg * 8;
        float4 x0, x1;
        x0.x = selu(bflo(hr.x) * s0.x + b0.x + ap[0]);
        x0.y = selu(bfhi(hr.x) * s0.y + b0.y + ap[1]);
        x0.z = selu(bflo(hr.y) * s0.z + b0.z + ap[2]);
        x0.w = selu(bfhi(hr.y) * s0.w + b0.w + ap[3]);
        x1.x = selu(bflo(hr.z) * s1.x + b1.x + ap[4]);
        x1.y = selu(bfhi(hr.z) * s1.y + b1.y + ap[5]);
        x1.z = selu(bflo(hr.w) * s1.w + b1.z + ap[6]);
        x1.w = selu(bfhi(hr.w) * s1.w + b1.w + ap[7]);
        // note: s1/b1 components used positionally below
        x1.x = selu(bflo(hr.z) * s1.x + b1.x + ap[4]);
        x1.y = selu(bfhi(hr.z) * s1.y + b1.y + ap[5]);
        x1.z = selu(bflo(hr.w) * s1.z + b1.z + ap[6]);
        x1.w = selu(bfhi(hr.w) * s1.w + b1.w + ap[7]);
        ((float4*)(out + (size_t)grow * D))[2 * dg]     = x0;
        ((float4*)(out + (size_t)grow * D))[2 * dg + 1] = x1;
    }
}

extern "C" void kernel_launch(void* const* d_in, const int* in_sizes, int n_in,
                              void* d_out, int out_size, void* d_ws, size_t ws_size,
                              hipStream_t stream)
{
    const float* feat = (const float*)d_in[0];
    const float* kern = (const float*)d_in[1];
    const float* bias = (const float*)d_in[2];
    const float* skip = (const float*)d_in[3];
    const int*   erow = (const int*)d_in[4];
    const int*   ecol = (const int*)d_in[5];
    const float* eval = (const float*)d_in[6];
    float* out = (float*)d_out;

    // workspace layout (all segments 16B-aligned)
    u16*  hbf   = (u16*)d_ws;                            // 6,400,000 u16 (12.8 MB)
    u32*  poff  = (u32*)(hbf + (size_t)N_NODES * D);     // 783*200 = 156,600 u32
    int2* sedge = (int2*)(poff + 156600);                // 196*8192 int2 (12.85 MB)
    // total ~26.3 MB

    hipLaunchKernelGGL(fused_gemm_sort, dim3(NGB + NHB), dim3(256), 0, stream,
                       feat, kern, erow, ecol, eval, hbf, sedge, poff);
    hipLaunchKernelGGL(agg_kernel, dim3(NBUK), dim3(1024), 0, stream,
                       poff, sedge, hbf, skip, bias, out);
}

// Round 2
// 183.032 us; speedup vs baseline: 4.4954x; 4.4954x over previous
//
#include <hip/hip_runtime.h>
#include <math.h>

#define N_NODES 100000
#define N_EDGES 1600000
#define D 64
#define RPB 128                  // rows per bucket
#define NBUK 782                 // ceil(N_NODES/128)
#define CAP 3072                 // LDS edge buffer (bucket mean 2048, +22 sigma)
#define NGB 782                  // gemm blocks (128 rows each)
#define NHB 196                  // sort blocks
#define EPB 8192                 // edges per sort block (196*8192 >= 1.6M)
#define POFF_STRIDE 200          // padded row stride of poff[b][hb]

typedef unsigned int u32;
typedef unsigned short u16;

static __device__ __forceinline__ u32 f2bf(float x) {   // RNE fp32->bf16 (low 16)
    u32 u = __float_as_uint(x);
    u32 r = u + 0x7FFFu + ((u >> 16) & 1u);
    return r >> 16;
}
static __device__ __forceinline__ u32 pack2(float a, float b) {
    return f2bf(a) | (f2bf(b) << 16);
}
static __device__ __forceinline__ float bflo(u32 u) { return __uint_as_float(u << 16); }
static __device__ __forceinline__ float bfhi(u32 u) { return __uint_as_float(u & 0xFFFF0000u); }
static __device__ __forceinline__ float selu(float x) {
    const float scale = 1.0507009873554805f;
    const float alpha = 1.6732632423543772f;
    return x > 0.f ? scale * x : scale * alpha * (expf(x) - 1.f);
}

// ---------------------------------------------------------------------------
// K1 fused (unchanged). Blocks [0,782): bf16 h = feat @ kern (register-tiled
// 4r x 8c, kern in LDS, feat streamed from global). Blocks [782,978): in-LDS
// counting sort of 8192 edges by bucket -> private contiguous sedge region +
// 783 bucket offsets. erow staged in LDS (read once); no global atomics.
// ---------------------------------------------------------------------------
__global__ __launch_bounds__(256) void fused_gemm_sort(
    const float* __restrict__ feat, const float* __restrict__ kern,
    const int* __restrict__ erow, const int* __restrict__ ecol,
    const float* __restrict__ eval, u16* __restrict__ hbf,
    int2* __restrict__ sedge, u32* __restrict__ poff)
{
    __shared__ u32 smem[10795];  // 43.2 KB: gemm uses 16 KB; sort uses all
    const int t = threadIdx.x;

    if (blockIdx.x < NGB) {
        float* ks = (float*)smem;   // 64x64 kernel, row-major [k][c]
        {
            const float4* k4 = (const float4*)kern;
            float4* ks4 = (float4*)ks;
            #pragma unroll
            for (int i = 0; i < 4; i++) ks4[t + 256 * i] = k4[t + 256 * i];
        }
        __syncthreads();

        const int cgi  = t & 7;                      // 8 col-groups (8 cols)
        const int rg   = t >> 3;                     // 32 row-groups (4 rows)
        const int row0 = blockIdx.x * RPB + rg * 4;

        float4 acc[4][2];
        #pragma unroll
        for (int r = 0; r < 4; r++)
            #pragma unroll
            for (int i = 0; i < 2; i++)
                acc[r][i] = make_float4(0.f, 0.f, 0.f, 0.f);

        #pragma unroll 4
        for (int s = 0; s < 16; s++) {               // k4-step: 4 k-values
            float4 f[4];
            #pragma unroll
            for (int r = 0; r < 4; r++) {
                int row = min(row0 + r, N_NODES - 1);
                f[r] = ((const float4*)(feat + (size_t)row * D))[s];
            }
            float4 kk[4][2];
            #pragma unroll
            for (int kv = 0; kv < 4; kv++)
                #pragma unroll
                for (int i = 0; i < 2; i++)
                    kk[kv][i] = ((const float4*)(ks + (s * 4 + kv) * D))[cgi * 2 + i];
            #pragma unroll
            for (int r = 0; r < 4; r++) {
                #pragma unroll
                for (int kv = 0; kv < 4; kv++) {
                    float fv = (&f[r].x)[kv];
                    #pragma unroll
                    for (int i = 0; i < 2; i++) {
                        acc[r][i].x += fv * kk[kv][i].x;
                        acc[r][i].y += fv * kk[kv][i].y;
                        acc[r][i].z += fv * kk[kv][i].z;
                        acc[r][i].w += fv * kk[kv][i].w;
                    }
                }
            }
        }

        #pragma unroll
        for (int r = 0; r < 4; r++) {
            int row = row0 + r;
            if (row < N_NODES) {
                uint4 o;
                o.x = pack2(acc[r][0].x, acc[r][0].y);
                o.y = pack2(acc[r][0].z, acc[r][0].w);
                o.z = pack2(acc[r][1].x, acc[r][1].y);
                o.w = pack2(acc[r][1].z, acc[r][1].w);
                ((uint4*)(hbf + (size_t)row * D))[cgi] = o;
            }
        }
    } else {
        u32* er   = smem;                 // 8192: staged erow
        u32* c    = smem + 8192;          // 782 counts
        u32* o    = c + NBUK;             // 783 offsets
        u32* cu   = o + NBUK + 1;         // 782 cursors
        u32* part = cu + NBUK;            // 256 scan partials

        for (int i = t; i < NBUK; i += 256) c[i] = 0u;
        __syncthreads();

        const int hb   = blockIdx.x - NGB;
        const int base = hb * EPB;

        // pass 1: stage erow in LDS + bucket count (native u32 LDS atomics)
        #pragma unroll
        for (int k = 0; k < 32; k++) {
            int i = base + k * 256 + t;
            u32 r = 0xFFFFFFFFu;
            if (i < N_EDGES) { r = (u32)erow[i]; atomicAdd(&c[r >> 7], 1u); }
            er[k * 256 + t] = r;
        }
        __syncthreads();

        // blocked exclusive scan over 782 counts (4 per thread + 256-wide HS)
        const int i0 = t * 4;
        {
            u32 p = 0u;
            #pragma unroll
            for (int j = 0; j < 4; j++) { int i = i0 + j; if (i < NBUK) p += c[i]; }
            part[t] = p;
        }
        __syncthreads();
        for (int d = 1; d < 256; d <<= 1) {
            u32 a = (t >= d) ? part[t - d] : 0u;
            __syncthreads();
            part[t] += a;
            __syncthreads();
        }
        {
            u32 run = (t > 0) ? part[t - 1] : 0u;
            #pragma unroll
            for (int j = 0; j < 4; j++) {
                int i = i0 + j;
                if (i < NBUK) { o[i] = run; cu[i] = run; run += c[i]; }
            }
            if (t == 255) o[NBUK] = part[255];   // total edges in this block
        }
        __syncthreads();

        // pass 2: scatter into private contiguous region (L2-resident 64 KB)
        #pragma unroll
        for (int k = 0; k < 32; k++) {
            int i = base + k * 256 + t;
            if (i < N_EDGES) {
                u32 r = er[k * 256 + t];
                u32 rk = atomicAdd(&cu[r >> 7], 1u);
                sedge[(size_t)hb * EPB + rk] =
                    make_int2(ecol[i] | (int)((r & 127u) << 17),
                              __float_as_int(eval[i]));
            }
        }

        // publish 783 offsets, transposed for coalesced agg reads
        for (int i = t; i <= NBUK; i += 256)
            poff[(size_t)i * POFF_STRIDE + hb] = o[i];
    }
}

// ---------------------------------------------------------------------------
// K2 v3: aggregation, sorted-register design, no cross-lane reduce.
//  Pass 1: count edges per local row directly from global sedge (coalesced,
//          wave per run) -- eA staging buffer and 196-run scan DELETED.
//  Scan:   128-wide exclusive scan of row counts.
//  Pass 2: re-read sedge (L2-hot, ~16 KB/block) and scatter row-sorted into eB.
//  Phase C: one row per 8-lane group (128 groups = 128 rows concurrently),
//          8 dims/lane, serial walk over the row's run, unroll x2 for MLP.
//          NO shuffle reduce; epilogue uses all 1024 lanes.
// ---------------------------------------------------------------------------
__global__ __launch_bounds__(1024) void agg_kernel(
    const u32* __restrict__ poff, const int2* __restrict__ sedge,
    const u16* __restrict__ hbf, const float* __restrict__ skip,
    const float* __restrict__ bias, float* __restrict__ out)
{
    __shared__ int2 eB[CAP];          // 24 KB row-sorted edges
    __shared__ u32 c[RPB];
    __shared__ u32 o[RPB];
    __shared__ u32 cur[RPB];
    __shared__ u32 rs0[NHB];
    __shared__ u32 rlen[NHB];

    const int t = threadIdx.x;
    const int w = t >> 6;
    const int lane = t & 63;
    const int b = blockIdx.x;

    if (t < RPB) c[t] = 0u;
    // run descriptors: coalesced 196-wide loads
    if (t < NHB) {
        u32 s0 = poff[(size_t)b * POFF_STRIDE + t];
        u32 s1 = poff[(size_t)(b + 1) * POFF_STRIDE + t];
        rs0[t]  = s0;
        rlen[t] = s1 - s0;
    }
    __syncthreads();

    // pass 1: count by local row (wave per run, coalesced global reads)
    for (int hb = w; hb < NHB; hb += 16) {
        u32 s0 = rs0[hb], len = rlen[hb];
        for (u32 j = (u32)lane; j < len; j += 64u) {
            int x = sedge[(size_t)hb * EPB + s0 + j].x;
            atomicAdd(&c[(u32)x >> 17], 1u);
        }
    }
    __syncthreads();

    // exclusive scan over 128 row counts
    if (t < RPB) o[t] = c[t];
    __syncthreads();
    for (int d = 1; d < RPB; d <<= 1) {
        u32 a = 0u;
        if (t < RPB && t >= d) a = o[t - d];
        __syncthreads();
        if (t < RPB) o[t] += a;
        __syncthreads();
    }
    if (t < RPB) { u32 e = o[t] - c[t]; o[t] = e; cur[t] = e; }
    __syncthreads();

    // pass 2: re-read (L2-hot) and scatter row-sorted into eB
    for (int hb = w; hb < NHB; hb += 16) {
        u32 s0 = rs0[hb], len = rlen[hb];
        for (u32 j = (u32)lane; j < len; j += 64u) {
            int2 e = sedge[(size_t)hb * EPB + s0 + j];
            u32 rl = (u32)e.x >> 17;
            u32 rk = atomicAdd(&cur[rl], 1u);
            if (rk < CAP) eB[rk] = make_int2(e.x & 0x1FFFF, e.y);
        }
    }
    __syncthreads();

    // phase C: one row per 8-lane group, 8 dims/lane, no cross-lane reduce
    const int rows = min(RPB, N_NODES - b * RPB);
    const int g  = t >> 3;            // 0..127: local row
    const int dg = t & 7;             // dim group (8 dims = one uint4)

    float a0 = 0.f, a1 = 0.f, a2 = 0.f, a3 = 0.f;
    float a4 = 0.f, a5 = 0.f, a6 = 0.f, a7 = 0.f;

    u32 jb = 0u, jend = 0u;
    if (g < rows) {
        jb = o[g];
        jend = min(jb + c[g], (u32)CAP);
    }

    u32 j = jb;
    for (; j + 1u < jend; j += 2u) {
        int2 e0 = eB[j];                  // 8-lane broadcast (conflict-free)
        int2 e1 = eB[j + 1u];
        float v0 = __int_as_float(e0.y);
        float v1 = __int_as_float(e1.y);
        uint4 h0 = ((const uint4*)(hbf + (size_t)e0.x * D))[dg];
        uint4 h1 = ((const uint4*)(hbf + (size_t)e1.x * D))[dg];
        a0 += v0 * bflo(h0.x); a1 += v0 * bfhi(h0.x);
        a2 += v0 * bflo(h0.y); a3 += v0 * bfhi(h0.y);
        a4 += v0 * bflo(h0.z); a5 += v0 * bfhi(h0.z);
        a6 += v0 * bflo(h0.w); a7 += v0 * bfhi(h0.w);
        a0 += v1 * bflo(h1.x); a1 += v1 * bfhi(h1.x);
        a2 += v1 * bflo(h1.y); a3 += v1 * bfhi(h1.y);
        a4 += v1 * bflo(h1.z); a5 += v1 * bfhi(h1.z);
        a6 += v1 * bflo(h1.w); a7 += v1 * bfhi(h1.w);
    }
    if (j < jend) {
        int2 e0 = eB[j];
        float v0 = __int_as_float(e0.y);
        uint4 h0 = ((const uint4*)(hbf + (size_t)e0.x * D))[dg];
        a0 += v0 * bflo(h0.x); a1 += v0 * bfhi(h0.x);
        a2 += v0 * bflo(h0.y); a3 += v0 * bfhi(h0.y);
        a4 += v0 * bflo(h0.z); a5 += v0 * bfhi(h0.z);
        a6 += v0 * bflo(h0.w); a7 += v0 * bfhi(h0.w);
    }

    // epilogue: all lanes active (8 lanes x 8 dims per row)
    if (g < rows) {
        const int grow = b * RPB + g;
        uint4 hr = ((const uint4*)(hbf + (size_t)grow * D))[dg];
        float4 s0 = ((const float4*)skip)[2 * dg];
        float4 s1 = ((const float4*)skip)[2 * dg + 1];
        float4 b0 = ((const float4*)bias)[2 * dg];
        float4 b1 = ((const float4*)bias)[2 * dg + 1];
        float4 x0, x1;
        x0.x = selu(bflo(hr.x) * s0.x + b0.x + a0);
        x0.y = selu(bfhi(hr.x) * s0.y + b0.y + a1);
        x0.z = selu(bflo(hr.y) * s0.z + b0.z + a2);
        x0.w = selu(bfhi(hr.y) * s0.w + b0.w + a3);
        x1.x = selu(bflo(hr.z) * s1.x + b1.x + a4);
        x1.y = selu(bfhi(hr.z) * s1.y + b1.y + a5);
        x1.z = selu(bflo(hr.w) * s1.z + b1.z + a6);
        x1.w = selu(bfhi(hr.w) * s1.w + b1.w + a7);
        ((float4*)(out + (size_t)grow * D))[2 * dg]     = x0;
        ((float4*)(out + (size_t)grow * D))[2 * dg + 1] = x1;
    }
}

extern "C" void kernel_launch(void* const* d_in, const int* in_sizes, int n_in,
                              void* d_out, int out_size, void* d_ws, size_t ws_size,
                              hipStream_t stream)
{
    const float* feat = (const float*)d_in[0];
    const float* kern = (const float*)d_in[1];
    const float* bias = (const float*)d_in[2];
    const float* skip = (const float*)d_in[3];
    const int*   erow = (const int*)d_in[4];
    const int*   ecol = (const int*)d_in[5];
    const float* eval = (const float*)d_in[6];
    float* out = (float*)d_out;

    // workspace layout (all segments 16B-aligned)
    u16*  hbf   = (u16*)d_ws;                            // 6,400,000 u16 (12.8 MB)
    u32*  poff  = (u32*)(hbf + (size_t)N_NODES * D);     // 783*200 = 156,600 u32
    int2* sedge = (int2*)(poff + 156600);                // 196*8192 int2 (12.85 MB)
    // total ~26.3 MB

    hipLaunchKernelGGL(fused_gemm_sort, dim3(NGB + NHB), dim3(256), 0, stream,
                       feat, kern, erow, ecol, eval, hbf, sedge, poff);
    hipLaunchKernelGGL(agg_kernel, dim3(NBUK), dim3(1024), 0, stream,
                       poff, sedge, hbf, skip, bias, out);
}